// Round 2
// 406.894 us; speedup vs baseline: 1.3149x; 1.3149x over previous
//
#include <hip/hip_runtime.h>

// QuantLinearBase: out = fakequant_i8(x) @ dequant_i4(W).T + bias
// Exact integer GEMM on the i8 MFMA pipe:
//   out[m,n] = (s * ws) * sum_k qx[m,k]*qw[n,k] + bias[n]
// qx = round(x/s) int8, qw in [-8,7] int8, s = amax/127. int32 accum exact.
//
// GEMM: 256x256 tile, 8 waves (2Mx4N), 4-deep LDS tile ring, counted
// vmcnt(8) boundaries (never 0 in main loop), LDS 16B-slot XOR swizzle via
// pre-swizzled global source + swizzled ds_read, setprio around MFMA
// clusters, XCD-aware block swizzle. Structure per T1/T2/T3+T4/T5 catalog.
// Aux path: atomic-free amax (block partials + 1-block reduce), reciprocal
// multiply in quant (no per-element fdiv).

typedef __attribute__((ext_vector_type(4))) int int32x4;

__device__ __forceinline__ void async_copy16(const void* gsrc, void* ldsdst) {
  __builtin_amdgcn_global_load_lds(
      (const __attribute__((address_space(1))) void*)gsrc,
      (__attribute__((address_space(3))) void*)ldsdst, 16, 0, 0);
}

// ---------------- Pass 1a: per-block partial amax(|x|) ----------------
__global__ void amax_kernel(const float* __restrict__ x,
                            float* __restrict__ partial, int n4) {
  int tid = blockIdx.x * blockDim.x + threadIdx.x;
  int stride = gridDim.x * blockDim.x;
  float m = 0.0f;
  const float4* x4 = (const float4*)x;
  for (int i = tid; i < n4; i += stride) {
    float4 v = x4[i];
    m = fmaxf(m, fmaxf(fmaxf(fabsf(v.x), fabsf(v.y)),
                       fmaxf(fabsf(v.z), fabsf(v.w))));
  }
#pragma unroll
  for (int off = 32; off > 0; off >>= 1)
    m = fmaxf(m, __shfl_down(m, off, 64));
  __shared__ float red[4];
  if ((threadIdx.x & 63) == 0) red[threadIdx.x >> 6] = m;
  __syncthreads();
  if (threadIdx.x == 0) {
    partial[blockIdx.x] = fmaxf(fmaxf(red[0], red[1]), fmaxf(red[2], red[3]));
  }
}

// ---------------- Pass 1b: reduce 512 partials -> amax (1 block) --------
__global__ void amax_reduce(const float* __restrict__ partial,
                            float* __restrict__ amax) {
  const int t = threadIdx.x;  // 256 threads
  float m = fmaxf(partial[t], partial[t + 256]);
#pragma unroll
  for (int off = 32; off > 0; off >>= 1)
    m = fmaxf(m, __shfl_down(m, off, 64));
  __shared__ float red[4];
  if ((t & 63) == 0) red[t >> 6] = m;
  __syncthreads();
  if (t == 0)
    *amax = fmaxf(fmaxf(red[0], red[1]), fmaxf(red[2], red[3]));
}

// ---------------- Pass 2: quantize x -> int8 ----------------
__global__ void quant_kernel(const float* __restrict__ x,
                             const float* __restrict__ amax_p,
                             unsigned* __restrict__ qx, int n4) {
  float s = *amax_p / 127.0f;  // same op as reference
  if (s == 0.0f) s = 1.0f;
  const float inv = 1.0f / s;  // one divide per thread, not per element
  int tid = blockIdx.x * blockDim.x + threadIdx.x;
  int stride = gridDim.x * blockDim.x;
  const float4* x4 = (const float4*)x;
  for (int i = tid; i < n4; i += stride) {
    float4 v = x4[i];
    int a = __float2int_rn(v.x * inv);  // RNE, matches jnp.round
    int b = __float2int_rn(v.y * inv);
    int c = __float2int_rn(v.z * inv);
    int d = __float2int_rn(v.w * inv);
    qx[i] = (unsigned)(a & 0xFF) | ((unsigned)(b & 0xFF) << 8) |
            ((unsigned)(c & 0xFF) << 16) | ((unsigned)(d & 0xFF) << 24);
  }
}

// ---------------- Pass 3: unpack int4 weights -> int8 [O,I] ----------------
__device__ __forceinline__ unsigned pack2(int q) {
  // byte0 (even col) = high nibble - 8, byte1 (odd col) = low nibble - 8
  unsigned hi = (unsigned)((((q >> 4) & 15) - 8) & 0xFF);
  unsigned lo = (unsigned)(((q & 15) - 8) & 0xFF);
  return hi | (lo << 8);
}

__global__ void repack_kernel(const int* __restrict__ qw,
                              uint2* __restrict__ w8, int n4) {
  int tid = blockIdx.x * blockDim.x + threadIdx.x;
  int stride = gridDim.x * blockDim.x;
  const int4* q4 = (const int4*)qw;
  for (int i = tid; i < n4; i += stride) {
    int4 q = q4[i];
    uint2 r;
    r.x = pack2(q.x) | (pack2(q.y) << 16);
    r.y = pack2(q.z) | (pack2(q.w) << 16);
    w8[i] = r;
  }
}

// ---------------- Pass 4: i8 MFMA GEMM, C = A[M,K] @ Bt[N,K]^T ----------
#define BM 256
#define BN 256
#define BKT 64             // K bytes per tile (one 16x16x64 K-slab)
#define TILE_B (BM * BKT)  // 16 KB per operand per tile

__global__ __launch_bounds__(512, 2) void gemm_i8(
    const char* __restrict__ A, const char* __restrict__ Bt,
    const float* __restrict__ bias, const float* __restrict__ amax_p,
    const float* __restrict__ wscale, float* __restrict__ C,
    int M, int N, int K) {
  // 4-deep tile ring: 4 x 16 KB per operand = 128 KB total
  __shared__ alignas(16) char As[4 * TILE_B];
  __shared__ alignas(16) char Bs[4 * TILE_B];

  const int tid = threadIdx.x;
  const int lane = tid & 63;
  const int wave = tid >> 6;
  const int wm = wave >> 2;  // 0..1  (128 rows each)
  const int wn = wave & 3;   // 0..3  (64 cols each)
  const int quad = lane >> 4;
  const int l16 = lane & 15;

  // XCD-aware bijective swizzle (nwg = 512, divisible by 8)
  const int cpx = gridDim.x >> 3;
  const int wg = (blockIdx.x & 7) * cpx + (blockIdx.x >> 3);
  const int bM = (wg >> 4) * BM;  // N/BN = 16 n-blocks
  const int bN = (wg & 15) * BN;

  const int NT = K >> 6;  // 64 tiles

  // ---- staging: thread covers phys chunk (row = tid>>2, slot = tid&3);
  // LDS dest is linear (global_load_lds constraint), so the XOR swizzle
  // slot ^= (row>>1)&3 is applied to the GLOBAL source column.
  const int srow = tid >> 2;  // 0..127 (2nd issue adds +128; same swz bits)
  const int scoff = (((tid & 3) ^ ((tid >> 3) & 3)) << 4);
  const char* aS = A + (size_t)(bM + srow) * K + scoff;
  const char* bS = Bt + (size_t)(bN + srow) * K + scoff;
  const size_t skip = (size_t)128 * K;
  char* aD = &As[tid * 16];
  char* bD = &Bs[tid * 16];

  // ---- prologue: stage tiles 0,1,2 (12 global_load_lds per thread)
  for (int tt = 0; tt < 3; ++tt) {
    const int boff = tt * TILE_B;
    const char* sa = aS + tt * BKT;
    const char* sb = bS + tt * BKT;
    async_copy16(sa, aD + boff);
    async_copy16(sa + skip, aD + boff + 8192);
    async_copy16(sb, bD + boff);
    async_copy16(sb + skip, bD + boff + 8192);
  }

  // ---- fragment read constants (swizzled ds_read address).
  // Within each 8-lane LDS service group this hits all 8 four-bank groups.
  const int xsl = ((quad ^ ((l16 >> 1) & 3)) << 4);
  const int arow0 = (wm << 7) + l16;
  const int brow0 = (wn << 6) + l16;

  int32x4 acc[8][4] = {};

  for (int t = 0; t < NT; ++t) {
    // boundary: counted vmcnt — per-wave 4 loads/tile; leaving the newest 8
    // outstanding means everything through tile t has landed (in-order
    // retirement). Barrier joins all waves' guarantees. Never vmcnt(0)
    // until the final tile.
    if (t + 2 < NT)
      asm volatile("s_waitcnt vmcnt(8)" ::: "memory");
    else if (t + 1 < NT)
      asm volatile("s_waitcnt vmcnt(4)" ::: "memory");
    else
      asm volatile("s_waitcnt vmcnt(0)" ::: "memory");
    __builtin_amdgcn_s_barrier();
    __builtin_amdgcn_sched_barrier(0);  // pin: no ds_read hoists above sync

    const char* Ab = &As[(t & 3) * TILE_B];
    const char* Bb = &Bs[(t & 3) * TILE_B];
    const int pboff = ((t + 3) & 3) * TILE_B;
    const bool do_stage = (t + 3 < NT);

    int32x4 af[4], bf[4];

    // ================= phase A: M-half 0 =================
#pragma unroll
    for (int i = 0; i < 4; ++i)
      af[i] = *(const int32x4*)(Ab + (arow0 + i * 16) * BKT + xsl);
#pragma unroll
    for (int j = 0; j < 4; ++j)
      bf[j] = *(const int32x4*)(Bb + (brow0 + j * 16) * BKT + xsl);
    if (do_stage) {  // stage A-halves of tile t+3 (uniform branch)
      const char* sa = aS + (t + 3) * BKT;
      async_copy16(sa, aD + pboff);
      async_copy16(sa + skip, aD + pboff + 8192);
    }
    __builtin_amdgcn_s_barrier();
    __builtin_amdgcn_s_setprio(1);
#pragma unroll
    for (int i = 0; i < 4; ++i)
#pragma unroll
      for (int j = 0; j < 4; ++j)
        acc[i][j] = __builtin_amdgcn_mfma_i32_16x16x64_i8(af[i], bf[j],
                                                          acc[i][j], 0, 0, 0);
    __builtin_amdgcn_s_setprio(0);

    // ================= phase B: M-half 1 =================
#pragma unroll
    for (int i = 0; i < 4; ++i)
      af[i] = *(const int32x4*)(Ab + (arow0 + 64 + i * 16) * BKT + xsl);
    if (do_stage) {  // stage B-halves of tile t+3
      const char* sb = bS + (t + 3) * BKT;
      async_copy16(sb, bD + pboff);
      async_copy16(sb + skip, bD + pboff + 8192);
    }
    __builtin_amdgcn_s_barrier();
    __builtin_amdgcn_s_setprio(1);
#pragma unroll
    for (int i = 0; i < 4; ++i)
#pragma unroll
      for (int j = 0; j < 4; ++j)
        acc[4 + i][j] = __builtin_amdgcn_mfma_i32_16x16x64_i8(
            af[i], bf[j], acc[4 + i][j], 0, 0, 0);
    __builtin_amdgcn_s_setprio(0);
  }

  // ---- epilogue: scale + bias (C/D layout: col = lane&15, row = quad*4+r)
  float s = *amax_p / 127.0f;
  if (s == 0.0f) s = 1.0f;
  const float cs = s * wscale[0];

#pragma unroll
  for (int f = 0; f < 8; ++f) {
#pragma unroll
    for (int j = 0; j < 4; ++j) {
      const int n = bN + (wn << 6) + j * 16 + l16;
#pragma unroll
      for (int r = 0; r < 4; ++r) {
        const int m = bM + (wm << 7) + f * 16 + quad * 4 + r;
        C[(size_t)m * N + n] = (float)acc[f][j][r] * cs + bias[n];
      }
    }
  }
}

extern "C" void kernel_launch(void* const* d_in, const int* in_sizes, int n_in,
                              void* d_out, int out_size, void* d_ws,
                              size_t ws_size, hipStream_t stream) {
  const float* x = (const float*)d_in[0];
  const int* qw = (const int*)d_in[1];
  const float* wscale = (const float*)d_in[2];
  const float* bias = (const float*)d_in[3];
  float* out = (float*)d_out;

  const int nx = in_sizes[0];       // B*S*I = 33,554,432
  const int npacked = in_sizes[1];  // O * I/2 = 8,388,608
  const int O = in_sizes[3];        // 4096
  const int I = (npacked / O) * 2;  // 4096
  const int M = nx / I;             // 8192

  float* amax = (float*)d_ws;                       // 4 B
  float* partial = (float*)((char*)d_ws + 256);     // 512 * 4 B
  char* qx = (char*)d_ws + 8192;
  char* w8 = qx + (size_t)nx;

  // no memset needed: partial[] and *amax are fully overwritten every run
  amax_kernel<<<512, 256, 0, stream>>>(x, partial, nx / 4);
  amax_reduce<<<1, 256, 0, stream>>>(partial, amax);
  quant_kernel<<<2048, 256, 0, stream>>>(x, amax, (unsigned*)qx, nx / 4);
  repack_kernel<<<1024, 256, 0, stream>>>(qw, (uint2*)w8, npacked / 4);

  const int nwg = (M / BM) * (O / BN);  // 32 * 16 = 512
  gemm_i8<<<nwg, 512, 0, stream>>>(qx, w8, bias, amax, wscale, out, M, O, I);
}

// Round 3
// 397.116 us; speedup vs baseline: 1.3473x; 1.0246x over previous
//
#include <hip/hip_runtime.h>

// QuantLinearBase: out = fakequant_i8(x) @ dequant_i4(W).T + bias
// Exact integer GEMM on the i8 MFMA pipe:
//   out[m,n] = (s * ws) * sum_k qx[m,k]*qw[n,k] + bias[n]
// qx = round(x/s) int8, qw in [-8,7] int8, s = amax/127. int32 accum exact.
//
// GEMM v3: 256x256 tile, 8 waves (2Mx4N), 4-deep LDS tile ring, counted
// vmcnt boundaries, LDS 16B-slot XOR swizzle (conflicts measured 0), AND
// register-level fragment pipelining: every MFMA cluster consumes fragments
// ds_read one cluster earlier, so LDS reads + staging overlap MFMA.
// One barrier per K-tile. Waits: lgkmcnt(4) / lgkmcnt(0) / vmcnt(6|4|0).

typedef __attribute__((ext_vector_type(4))) int int32x4;

__device__ __forceinline__ void async_copy16(const void* gsrc, void* ldsdst) {
  __builtin_amdgcn_global_load_lds(
      (const __attribute__((address_space(1))) void*)gsrc,
      (__attribute__((address_space(3))) void*)ldsdst, 16, 0, 0);
}

// ---------------- Pass 1: per-block partial amax(|x|) ----------------
__global__ void amax_kernel(const float* __restrict__ x,
                            float* __restrict__ partial, int n4) {
  int tid = blockIdx.x * blockDim.x + threadIdx.x;
  int stride = gridDim.x * blockDim.x;
  float m = 0.0f;
  const float4* x4 = (const float4*)x;
  for (int i = tid; i < n4; i += stride) {
    float4 v = x4[i];
    m = fmaxf(m, fmaxf(fmaxf(fabsf(v.x), fabsf(v.y)),
                       fmaxf(fabsf(v.z), fabsf(v.w))));
  }
#pragma unroll
  for (int off = 32; off > 0; off >>= 1)
    m = fmaxf(m, __shfl_down(m, off, 64));
  __shared__ float red[4];
  if ((threadIdx.x & 63) == 0) red[threadIdx.x >> 6] = m;
  __syncthreads();
  if (threadIdx.x == 0) {
    partial[blockIdx.x] = fmaxf(fmaxf(red[0], red[1]), fmaxf(red[2], red[3]));
  }
}

// ---------------- Pass 2: quantize x -> int8 (amax reduce folded in) ----
// Every block redundantly reduces the 512 partials (2 KB, L2-hit) -> no
// separate 1-block reduce launch. Block 0 publishes the scalar for gemm.
__global__ void quant_kernel(const float* __restrict__ x,
                             const float* __restrict__ partial,
                             float* __restrict__ amax_out,
                             unsigned* __restrict__ qx, int n4) {
  const int t = threadIdx.x;  // 256 threads
  float m = fmaxf(partial[t], partial[t + 256]);
#pragma unroll
  for (int off = 32; off > 0; off >>= 1)
    m = fmaxf(m, __shfl_down(m, off, 64));
  __shared__ float red[4];
  if ((t & 63) == 0) red[t >> 6] = m;
  __syncthreads();
  __shared__ float s_bcast;
  if (t == 0) {
    float amax = fmaxf(fmaxf(red[0], red[1]), fmaxf(red[2], red[3]));
    if (blockIdx.x == 0) *amax_out = amax;
    float s = amax / 127.0f;  // same op as reference
    if (s == 0.0f) s = 1.0f;
    s_bcast = 1.0f / s;
  }
  __syncthreads();
  const float inv = s_bcast;

  int tid = blockIdx.x * blockDim.x + t;
  int stride = gridDim.x * blockDim.x;
  const float4* x4 = (const float4*)x;
  for (int i = tid; i < n4; i += stride) {
    float4 v = x4[i];
    int a = __float2int_rn(v.x * inv);  // RNE, matches jnp.round
    int b = __float2int_rn(v.y * inv);
    int c = __float2int_rn(v.z * inv);
    int d = __float2int_rn(v.w * inv);
    qx[i] = (unsigned)(a & 0xFF) | ((unsigned)(b & 0xFF) << 8) |
            ((unsigned)(c & 0xFF) << 16) | ((unsigned)(d & 0xFF) << 24);
  }
}

// ---------------- Pass 3: unpack int4 weights -> int8 [O,I] ----------------
__device__ __forceinline__ unsigned pack2(int q) {
  // byte0 (even col) = high nibble - 8, byte1 (odd col) = low nibble - 8
  unsigned hi = (unsigned)((((q >> 4) & 15) - 8) & 0xFF);
  unsigned lo = (unsigned)(((q & 15) - 8) & 0xFF);
  return hi | (lo << 8);
}

__global__ void repack_kernel(const int* __restrict__ qw,
                              uint2* __restrict__ w8, int n4) {
  int tid = blockIdx.x * blockDim.x + threadIdx.x;
  int stride = gridDim.x * blockDim.x;
  const int4* q4 = (const int4*)qw;
  for (int i = tid; i < n4; i += stride) {
    int4 q = q4[i];
    uint2 r;
    r.x = pack2(q.x) | (pack2(q.y) << 16);
    r.y = pack2(q.z) | (pack2(q.w) << 16);
    w8[i] = r;
  }
}

// ---------------- Pass 4: i8 MFMA GEMM, C = A[M,K] @ Bt[N,K]^T ----------
#define BM 256
#define BN 256
#define BKT 64             // K bytes per tile (one 16x16x64 K-slab)
#define TILE_B (BM * BKT)  // 16 KB per operand per tile

// One K-tile, fragment-pipelined. CUR_AL/CUR_BF were loaded during the
// previous tile's phase B; NXT_AL/NXT_BF get tile t+1's fragments.
// Assumes NT >= 4 and NT even (K multiple of 128; here K=4096 -> NT=64).
#define TILE_BODY(t, CUR_AL, CUR_BF, NXT_AL, NXT_BF)                          \
  {                                                                           \
    const char* Ab = &As[((t) & 3) * TILE_B];                                 \
    /* ---- phase A: read af_hi(t) (consumed in phase B), stage, MFMA ---- */ \
    _Pragma("unroll") for (int i = 0; i < 4; ++i) afH[i] =                    \
        *(const int32x4*)(Ab + (arow0 + 64 + i * 16) * BKT + xsl);            \
    if ((t) + 3 < NT) {                                                       \
      const char* sa = aS + ((t) + 3) * BKT;                                  \
      char* ad = aD + (((t) + 3) & 3) * TILE_B;                               \
      async_copy16(sa, ad);                                                   \
      async_copy16(sa + skip, ad + 8192);                                     \
    }                                                                         \
    /* CUR frags (8 reads, issued last tile) done; afH's 4 still in flight */ \
    asm volatile("s_waitcnt lgkmcnt(4)" ::: "memory");                        \
    __builtin_amdgcn_s_setprio(1);                                            \
    _Pragma("unroll") for (int i = 0; i < 4; ++i)                             \
        _Pragma("unroll") for (int j = 0; j < 4; ++j) acc[i][j] =             \
            __builtin_amdgcn_mfma_i32_16x16x64_i8(CUR_AL[i], CUR_BF[j],       \
                                                  acc[i][j], 0, 0, 0);        \
    __builtin_amdgcn_s_setprio(0);                                            \
    /* ---- phase B: boundary, read tile t+1 frags, stage, MFMA ---- */       \
    if ((t) + 1 < NT) {                                                       \
      /* drain my ds_reads (afH issued 16 MFMA ago: free) so every wave's     \
         slot reads are complete before anyone stages past the barrier */     \
      asm volatile("s_waitcnt lgkmcnt(0)" ::: "memory");                      \
      /* outstanding after tile t+1's loads: stage(t+2) 4 + stage(t+3)A 2 */  \
      if ((t) + 4 <= NT)                                                      \
        asm volatile("s_waitcnt vmcnt(6)" ::: "memory");                      \
      else if ((t) + 3 <= NT)                                                 \
        asm volatile("s_waitcnt vmcnt(4)" ::: "memory");                      \
      else                                                                    \
        asm volatile("s_waitcnt vmcnt(0)" ::: "memory");                      \
      __builtin_amdgcn_s_barrier();                                           \
      __builtin_amdgcn_sched_barrier(0); /* no read hoists above barrier */   \
      const char* Abn = &As[(((t) + 1) & 3) * TILE_B];                        \
      const char* Bbn = &Bs[(((t) + 1) & 3) * TILE_B];                        \
      _Pragma("unroll") for (int i = 0; i < 4; ++i) NXT_AL[i] =               \
          *(const int32x4*)(Abn + (arow0 + i * 16) * BKT + xsl);              \
      _Pragma("unroll") for (int j = 0; j < 4; ++j) NXT_BF[j] =               \
          *(const int32x4*)(Bbn + (brow0 + j * 16) * BKT + xsl);              \
    }                                                                         \
    if ((t) + 3 < NT) {                                                       \
      const char* sb = bS + ((t) + 3) * BKT;                                  \
      char* bd = bD + (((t) + 3) & 3) * TILE_B;                               \
      async_copy16(sb, bd);                                                   \
      async_copy16(sb + skip, bd + 8192);                                     \
    }                                                                         \
    __builtin_amdgcn_s_setprio(1);                                            \
    _Pragma("unroll") for (int i = 0; i < 4; ++i)                             \
        _Pragma("unroll") for (int j = 0; j < 4; ++j) acc[4 + i][j] =         \
            __builtin_amdgcn_mfma_i32_16x16x64_i8(afH[i], CUR_BF[j],          \
                                                  acc[4 + i][j], 0, 0, 0);    \
    __builtin_amdgcn_s_setprio(0);                                            \
  }

__global__ __launch_bounds__(512, 2) void gemm_i8(
    const char* __restrict__ A, const char* __restrict__ Bt,
    const float* __restrict__ bias, const float* __restrict__ amax_p,
    const float* __restrict__ wscale, float* __restrict__ C,
    int M, int N, int K) {
  // 4-deep tile ring: 4 x 16 KB per operand = 128 KB total
  __shared__ alignas(16) char As[4 * TILE_B];
  __shared__ alignas(16) char Bs[4 * TILE_B];

  const int tid = threadIdx.x;
  const int lane = tid & 63;
  const int wave = tid >> 6;
  const int wm = wave >> 2;  // 0..1  (128 rows each)
  const int wn = wave & 3;   // 0..3  (64 cols each)
  const int quad = lane >> 4;
  const int l16 = lane & 15;

  // XCD-aware bijective swizzle (nwg = 512, divisible by 8)
  const int cpx = gridDim.x >> 3;
  const int wg = (blockIdx.x & 7) * cpx + (blockIdx.x >> 3);
  const int bM = (wg >> 4) * BM;  // N/BN = 16 n-blocks
  const int bN = (wg & 15) * BN;

  const int NT = K >> 6;  // 64 tiles

  // ---- staging: thread covers phys chunk (row = tid>>2, slot = tid&3);
  // LDS dest is linear (global_load_lds constraint), so the XOR swizzle
  // slot ^= (row>>1)&3 is applied to the GLOBAL source column.
  const int srow = tid >> 2;  // 0..127 (2nd issue adds +128; same swz bits)
  const int scoff = (((tid & 3) ^ ((tid >> 3) & 3)) << 4);
  const char* aS = A + (size_t)(bM + srow) * K + scoff;
  const char* bS = Bt + (size_t)(bN + srow) * K + scoff;
  const size_t skip = (size_t)128 * K;
  char* aD = &As[tid * 16];
  char* bD = &Bs[tid * 16];

  // ---- prologue: stage tiles 0,1,2 (12 global_load_lds per thread)
  for (int tt = 0; tt < 3; ++tt) {
    const int boff = tt * TILE_B;
    const char* sa = aS + tt * BKT;
    const char* sb = bS + tt * BKT;
    async_copy16(sa, aD + boff);
    async_copy16(sa + skip, aD + boff + 8192);
    async_copy16(sb, bD + boff);
    async_copy16(sb + skip, bD + boff + 8192);
  }

  // ---- fragment read constants (swizzled ds_read address).
  const int xsl = ((quad ^ ((l16 >> 1) & 3)) << 4);
  const int arow0 = (wm << 7) + l16;
  const int brow0 = (wn << 6) + l16;

  int32x4 acc[8][4] = {};
  int32x4 afL0[4], bf0[4], afL1[4], bf1[4], afH[4];

  // tile 0 landed (12 issued; newest 8 = tiles 1,2); then all waves' loads
  asm volatile("s_waitcnt vmcnt(8)" ::: "memory");
  __builtin_amdgcn_s_barrier();
  __builtin_amdgcn_sched_barrier(0);

  // initial fragments for tile 0 phase A (8 reads -> lgkm order matches loop)
#pragma unroll
  for (int i = 0; i < 4; ++i)
    afL0[i] = *(const int32x4*)(&As[0] + (arow0 + i * 16) * BKT + xsl);
#pragma unroll
  for (int j = 0; j < 4; ++j)
    bf0[j] = *(const int32x4*)(&Bs[0] + (brow0 + j * 16) * BKT + xsl);

  for (int t = 0; t < NT; t += 2) {
    TILE_BODY(t, afL0, bf0, afL1, bf1);
    TILE_BODY(t + 1, afL1, bf1, afL0, bf0);
  }

  // ---- epilogue: scale + bias (C/D layout: col = lane&15, row = quad*4+r)
  float s = *amax_p / 127.0f;
  if (s == 0.0f) s = 1.0f;
  const float cs = s * wscale[0];

#pragma unroll
  for (int f = 0; f < 8; ++f) {
#pragma unroll
    for (int j = 0; j < 4; ++j) {
      const int n = bN + (wn << 6) + j * 16 + l16;
#pragma unroll
      for (int r = 0; r < 4; ++r) {
        const int m = bM + (wm << 7) + f * 16 + quad * 4 + r;
        C[(size_t)m * N + n] = (float)acc[f][j][r] * cs + bias[n];
      }
    }
  }
}

extern "C" void kernel_launch(void* const* d_in, const int* in_sizes, int n_in,
                              void* d_out, int out_size, void* d_ws,
                              size_t ws_size, hipStream_t stream) {
  const float* x = (const float*)d_in[0];
  const int* qw = (const int*)d_in[1];
  const float* wscale = (const float*)d_in[2];
  const float* bias = (const float*)d_in[3];
  float* out = (float*)d_out;

  const int nx = in_sizes[0];       // B*S*I = 33,554,432
  const int npacked = in_sizes[1];  // O * I/2 = 8,388,608
  const int O = in_sizes[3];        // 4096
  const int I = (npacked / O) * 2;  // 4096
  const int M = nx / I;             // 8192

  float* amax = (float*)d_ws;                    // 4 B
  float* partial = (float*)((char*)d_ws + 256);  // 512 * 4 B
  char* qx = (char*)d_ws + 8192;
  char* w8 = qx + (size_t)nx;

  // partial[] and *amax are fully overwritten every run; no memset needed
  amax_kernel<<<512, 256, 0, stream>>>(x, partial, nx / 4);
  quant_kernel<<<2048, 256, 0, stream>>>(x, partial, amax, (unsigned*)qx,
                                         nx / 4);
  repack_kernel<<<1024, 256, 0, stream>>>(qw, (uint2*)w8, npacked / 4);

  const int nwg = (M / BM) * (O / BN);  // 32 * 16 = 512
  gemm_i8<<<nwg, 512, 0, stream>>>(qx, w8, bias, amax, wscale, out, M, O, I);
}